// Round 1
// baseline (303.197 us; speedup 1.0000x reference)
//
#include <hip/hip_runtime.h>

// A2aSparseMLP: B=1, S=2048, H=1024, I=1024, E=8, TOP_K=2, ALPHA=1.702, LIMIT=7
// Sparse grouped-GEMM implementation, bf16 MFMA 16x16x32.

#define Sd 2048
#define Hd 1024
#define Id 1024
#define Fd 2048

typedef __bf16 bf16x8 __attribute__((ext_vector_type(8)));
typedef float f32x4 __attribute__((ext_vector_type(4)));

__device__ __forceinline__ f32x4 mfma_bf16(bf16x8 a, bf16x8 b, f32x4 c) {
  return __builtin_amdgcn_mfma_f32_16x16x32_bf16(a, b, c, 0, 0, 0);
}

// ---------------- router: logits, top2, softmax, scatter lists ----------------
__global__ __launch_bounds__(256) void k_router(
    const float* __restrict__ x, const float* __restrict__ rw,
    const float* __restrict__ rb, float* __restrict__ scores,
    float* __restrict__ topw, int* __restrict__ cnt, int* __restrict__ assign) {
  const int lane = threadIdx.x & 63;
  const int t = blockIdx.x * 4 + (threadIdx.x >> 6);
  float acc[8];
#pragma unroll
  for (int e = 0; e < 8; ++e) acc[e] = 0.f;
  const float* xr = x + (size_t)t * Hd;
#pragma unroll
  for (int j = 0; j < 16; ++j) {
    int h = j * 64 + lane;
    float xv = xr[h];
    const float4* wp = (const float4*)(rw + h * 8);
    float4 w0 = wp[0], w1 = wp[1];
    acc[0] += xv * w0.x; acc[1] += xv * w0.y;
    acc[2] += xv * w0.z; acc[3] += xv * w0.w;
    acc[4] += xv * w1.x; acc[5] += xv * w1.y;
    acc[6] += xv * w1.z; acc[7] += xv * w1.w;
  }
#pragma unroll
  for (int m = 32; m >= 1; m >>= 1) {
#pragma unroll
    for (int e = 0; e < 8; ++e) acc[e] += __shfl_xor(acc[e], m, 64);
  }
  if (lane == 0) {
    float lg[8];
#pragma unroll
    for (int e = 0; e < 8; ++e) lg[e] = acc[e] + rb[e];
    int i0 = 0; float v0 = lg[0];
#pragma unroll
    for (int e = 1; e < 8; ++e) if (lg[e] > v0) { v0 = lg[e]; i0 = e; }
    int i1 = -1; float v1 = -3.4e38f;
#pragma unroll
    for (int e = 0; e < 8; ++e) if (e != i0 && lg[e] > v1) { v1 = lg[e]; i1 = e; }
    float e1 = __expf(v1 - v0);
    float s = 1.f + e1;
    float w0 = 1.f / s, w1v = e1 / s;
#pragma unroll
    for (int e = 0; e < 8; ++e)
      scores[t * 8 + e] = (e == i0) ? w0 : ((e == i1) ? w1v : 0.f);
    topw[t * 2] = w0;
    topw[t * 2 + 1] = w1v;
    int s0 = atomicAdd(&cnt[i0], 1); assign[i0 * 2048 + s0] = t * 2;
    int s1 = atomicAdd(&cnt[i1], 1); assign[i1 * 2048 + s1] = t * 2 + 1;
  }
}

// ------ pre-arrange gate_up weights -> bf16, MFMA-B-fragment order ------
// Layout: w1f[(((e*128 + v)*32 + k32)*64 + lane)*8 + j]
//   v = virtual nfrag: v=2P -> gate cols 2*(P*16+c), v=2P+1 -> up cols +1
//   element = W[e][k32*32 + (lane>>4)*8 + j][gucol(v, lane&15)]
__global__ __launch_bounds__(256) void k_pre1(const float* __restrict__ wgu,
                                              __bf16* __restrict__ w1f) {
  int w = blockIdx.x * 4 + (threadIdx.x >> 6);  // 0..16383 = e(8) x P(64) x k32(32)
  int lane = threadIdx.x & 63;
  int k32 = w & 31;
  int P = (w >> 5) & 63;
  int e = w >> 11;
  int i = P * 16 + (lane & 15);
  int kb = k32 * 32 + ((lane >> 4) * 8);
  const float* base = wgu + ((size_t)e * 1024 + kb) * 2048 + 2 * i;
  bf16x8 g, u;
#pragma unroll
  for (int j = 0; j < 8; ++j) {
    float2 v = *(const float2*)(base + (size_t)j * 2048);
    g[j] = (__bf16)v.x;
    u[j] = (__bf16)v.y;
  }
  size_t o = (((size_t)(e * 128 + 2 * P) * 32 + k32) * 64 + lane) * 8;
  *(bf16x8*)(w1f + o) = g;
  *(bf16x8*)(w1f + o + 32 * 512) = u;  // vfrag+1
}

// ------ pre-arrange down weights -> bf16 fragment order ------
__global__ __launch_bounds__(256) void k_pre2(const float* __restrict__ wdn,
                                              __bf16* __restrict__ w2f) {
  int w = blockIdx.x * 4 + (threadIdx.x >> 6);  // e(8) x F(64) x k32(32)
  int lane = threadIdx.x & 63;
  int k32 = w & 31;
  int F = (w >> 5) & 63;
  int e = w >> 11;
  int n = F * 16 + (lane & 15);
  int kb = k32 * 32 + ((lane >> 4) * 8);
  const float* base = wdn + ((size_t)e * 1024 + kb) * 1024 + n;
  bf16x8 b;
#pragma unroll
  for (int j = 0; j < 8; ++j) b[j] = (__bf16)base[(size_t)j * 1024];
  size_t o = (((size_t)(e * 64 + F) * 32 + k32) * 64 + lane) * 8;
  *(bf16x8*)(w2f + o) = b;
}

// ------ GEMM1: gathered X @ Wgu -> bias -> clamp -> GLU -> abuf (bf16) ------
// tile: 128 assignments x 128 virtual cols (= 64 act cols), 4 waves 2x2 quadrants
__global__ __launch_bounds__(256) void k_gemm1(
    const float* __restrict__ x, const __bf16* __restrict__ w1f,
    const float* __restrict__ gub, const int* __restrict__ cnt,
    const int* __restrict__ assign, __bf16* __restrict__ abuf) {
  const int e = blockIdx.x >> 4;
  const int mt = blockIdx.x & 15;
  const int it = blockIdx.y;  // 64 act-cols per tile
  const int n = cnt[e];
  if (mt * 128 >= n) return;
  __shared__ __bf16 Xs[128][40];  // pad 40 -> 2-way max bank alias
  __shared__ __bf16 Bs[8 * 512];  // 8 frag blocks, lane-linear (conflict-free)
  __shared__ int ent[128];
  const int tid = threadIdx.x;
  if (tid < 128) {
    int slot = mt * 128 + tid;
    ent[tid] = (slot < n) ? assign[e * 2048 + slot] : -1;
  }
  __syncthreads();
  const int r = tid >> 1, seg = tid & 1;
  const int tok = (ent[r] >= 0) ? (ent[r] >> 1) : 0;
  const float* xrow = x + (size_t)tok * Hd + seg * 16;
  const __bf16* wbase = w1f + (size_t)(e * 128 + it * 8) * (32 * 512);
  const int lane = tid & 63, wid = tid >> 6;
  const int wm = wid >> 1, wn = wid & 1;
  f32x4 acc[4][4];
#pragma unroll
  for (int a = 0; a < 4; ++a)
#pragma unroll
    for (int b = 0; b < 4; ++b) acc[a][b] = (f32x4){0.f, 0.f, 0.f, 0.f};

  for (int ks = 0; ks < 32; ++ks) {
    __syncthreads();
    {  // stage X: gather rows, f32 -> bf16
      const float4* p = (const float4*)(xrow + ks * 32);
      float4 f0 = p[0], f1 = p[1], f2 = p[2], f3 = p[3];
      bf16x8 s0, s1;
      s0[0] = (__bf16)f0.x; s0[1] = (__bf16)f0.y; s0[2] = (__bf16)f0.z; s0[3] = (__bf16)f0.w;
      s0[4] = (__bf16)f1.x; s0[5] = (__bf16)f1.y; s0[6] = (__bf16)f1.z; s0[7] = (__bf16)f1.w;
      s1[0] = (__bf16)f2.x; s1[1] = (__bf16)f2.y; s1[2] = (__bf16)f2.z; s1[3] = (__bf16)f2.w;
      s1[4] = (__bf16)f3.x; s1[5] = (__bf16)f3.y; s1[6] = (__bf16)f3.z; s1[7] = (__bf16)f3.w;
      *(bf16x8*)&Xs[r][seg * 16] = s0;
      *(bf16x8*)&Xs[r][seg * 16 + 8] = s1;
    }
#pragma unroll
    for (int it2 = 0; it2 < 2; ++it2) {  // stage B: linear frag copy
      int idx = it2 * 256 + tid;
      bf16x8 v = *(const bf16x8*)(wbase + ((size_t)(idx >> 6) * 32 + ks) * 512 + (idx & 63) * 8);
      *(bf16x8*)&Bs[idx * 8] = v;
    }
    __syncthreads();
    bf16x8 a[4], b[4];
#pragma unroll
    for (int mi = 0; mi < 4; ++mi)
      a[mi] = *(const bf16x8*)&Xs[wm * 64 + mi * 16 + (lane & 15)][(lane >> 4) * 8];
#pragma unroll
    for (int ni = 0; ni < 4; ++ni)
      b[ni] = *(const bf16x8*)&Bs[((wn * 4 + ni) * 64 + lane) * 8];
#pragma unroll
    for (int mi = 0; mi < 4; ++mi)
#pragma unroll
      for (int ni = 0; ni < 4; ++ni)
        acc[mi][ni] = mfma_bf16(a[mi], b[ni], acc[mi][ni]);
  }
  // epilogue: acc[mi][2p]=gate, acc[mi][2p+1]=up for act col i (same lane)
#pragma unroll
  for (int pi = 0; pi < 2; ++pi) {
    const int i = it * 64 + (wn * 2 + pi) * 16 + (lane & 15);
    const float bg = gub[e * 2048 + 2 * i];
    const float bu = gub[e * 2048 + 2 * i + 1];
#pragma unroll
    for (int mi = 0; mi < 4; ++mi) {
      f32x4 ag = acc[mi][2 * pi];
      f32x4 au = acc[mi][2 * pi + 1];
#pragma unroll
      for (int rr = 0; rr < 4; ++rr) {
        int m = wm * 64 + mi * 16 + (lane >> 4) * 4 + rr;
        int en = ent[m];
        if (en >= 0) {
          float g = fminf(ag[rr] + bg, 7.f);
          float u = fminf(fmaxf(au[rr] + bu, -7.f), 7.f);
          float sg = 1.f / (1.f + __expf(-1.702f * g));
          abuf[(size_t)en * Id + i] = (__bf16)((u + 1.f) * (g * sg));
        }
      }
    }
  }
}

// ------ GEMM2: abuf @ Wdown -> w*(acc+bias) -> atomicAdd out ------
__global__ __launch_bounds__(256) void k_gemm2(
    const __bf16* __restrict__ abuf, const __bf16* __restrict__ w2f,
    const float* __restrict__ dnb, const int* __restrict__ cnt,
    const int* __restrict__ assign, const float* __restrict__ topw,
    float* __restrict__ out) {
  const int e = blockIdx.x >> 4;
  const int mt = blockIdx.x & 15;
  const int ht = blockIdx.y;  // 128 h-cols per tile
  const int n = cnt[e];
  if (mt * 128 >= n) return;
  __shared__ __bf16 Xs[128][40];
  __shared__ __bf16 Bs[8 * 512];
  __shared__ int ent[128];
  __shared__ float wgt[128];
  const int tid = threadIdx.x;
  if (tid < 128) {
    int slot = mt * 128 + tid;
    int en = (slot < n) ? assign[e * 2048 + slot] : -1;
    ent[tid] = en;
    wgt[tid] = (en >= 0) ? topw[en] : 0.f;
  }
  __syncthreads();
  const int r = tid >> 1, seg = tid & 1;
  const int ro = (ent[r] >= 0) ? ent[r] : 0;
  const __bf16* arow = abuf + (size_t)ro * Id + seg * 16;
  const __bf16* wbase = w2f + (size_t)(e * 64 + ht * 8) * (32 * 512);
  const int lane = tid & 63, wid = tid >> 6;
  const int wm = wid >> 1, wn = wid & 1;
  f32x4 acc[4][4];
#pragma unroll
  for (int a = 0; a < 4; ++a)
#pragma unroll
    for (int b = 0; b < 4; ++b) acc[a][b] = (f32x4){0.f, 0.f, 0.f, 0.f};

  for (int ks = 0; ks < 32; ++ks) {
    __syncthreads();
    {  // stage A rows (already bf16)
      bf16x8 s0 = *(const bf16x8*)(arow + ks * 32);
      bf16x8 s1 = *(const bf16x8*)(arow + ks * 32 + 8);
      *(bf16x8*)&Xs[r][seg * 16] = s0;
      *(bf16x8*)&Xs[r][seg * 16 + 8] = s1;
    }
#pragma unroll
    for (int it2 = 0; it2 < 2; ++it2) {
      int idx = it2 * 256 + tid;
      bf16x8 v = *(const bf16x8*)(wbase + ((size_t)(idx >> 6) * 32 + ks) * 512 + (idx & 63) * 8);
      *(bf16x8*)&Bs[idx * 8] = v;
    }
    __syncthreads();
    bf16x8 a[4], b[4];
#pragma unroll
    for (int mi = 0; mi < 4; ++mi)
      a[mi] = *(const bf16x8*)&Xs[wm * 64 + mi * 16 + (lane & 15)][(lane >> 4) * 8];
#pragma unroll
    for (int ni = 0; ni < 4; ++ni)
      b[ni] = *(const bf16x8*)&Bs[((wn * 4 + ni) * 64 + lane) * 8];
#pragma unroll
    for (int mi = 0; mi < 4; ++mi)
#pragma unroll
      for (int ni = 0; ni < 4; ++ni)
        acc[mi][ni] = mfma_bf16(a[mi], b[ni], acc[mi][ni]);
  }
#pragma unroll
  for (int ni = 0; ni < 4; ++ni) {
    const int nn = ht * 128 + wn * 64 + ni * 16 + (lane & 15);
    const float bias = dnb[e * 1024 + nn];
#pragma unroll
    for (int mi = 0; mi < 4; ++mi) {
#pragma unroll
      for (int rr = 0; rr < 4; ++rr) {
        int m = wm * 64 + mi * 16 + (lane >> 4) * 4 + rr;
        int en = ent[m];
        if (en >= 0)
          atomicAdd(out + (size_t)(en >> 1) * Hd + nn,
                    wgt[m] * (acc[mi][ni][rr] + bias));
      }
    }
  }
}

extern "C" void kernel_launch(void* const* d_in, const int* in_sizes, int n_in,
                              void* d_out, int out_size, void* d_ws, size_t ws_size,
                              hipStream_t stream) {
  const float* x   = (const float*)d_in[0];
  const float* rw  = (const float*)d_in[1];
  const float* rb  = (const float*)d_in[2];
  const float* wgu = (const float*)d_in[3];
  const float* gub = (const float*)d_in[4];
  const float* wdn = (const float*)d_in[5];
  const float* dnb = (const float*)d_in[6];
  float* out = (float*)d_out;
  float* scores = out + (size_t)Sd * Hd;

  char* ws = (char*)d_ws;
  int* cnt       = (int*)ws;                       // 32 B
  int* assign    = (int*)(ws + 256);               // 8*2048*4 = 64 KiB
  float* topw    = (float*)(ws + 65792);           // 2048*2*4 = 16 KiB
  __bf16* abuf   = (__bf16*)(ws + 131072);         // 4096*1024*2 = 8 MiB
  __bf16* w1f    = (__bf16*)(ws + ((size_t)16 << 20));            // 32 MiB
  __bf16* w2f    = (__bf16*)(ws + ((size_t)16 << 20) + 33554432); // 16 MiB

  hipMemsetAsync(out, 0, (size_t)Sd * Hd * sizeof(float), stream);
  hipMemsetAsync(cnt, 0, 32, stream);

  k_router<<<512, 256, 0, stream>>>(x, rw, rb, scores, topw, cnt, assign);
  k_pre1<<<4096, 256, 0, stream>>>(wgu, w1f);
  k_pre2<<<4096, 256, 0, stream>>>(wdn, w2f);
  k_gemm1<<<dim3(128, 16), 256, 0, stream>>>(x, w1f, gub, cnt, assign, abuf);
  k_gemm2<<<dim3(128, 8), 256, 0, stream>>>(abuf, w2f, dnb, cnt, assign, topw, out);
}